// Round 9
// baseline (257.658 us; speedup 1.0000x reference)
//
#include <hip/hip_runtime.h>

#define N_NODES 4096
#define N_EDGES 65536
#define MID 32
#define BN_EPS 1e-5f

// ---- workspace layout ----
// float offsets:
#define WS_RSUM    0
#define WS_RSUMSQ  1
#define WS_ALPHA1  272
#define WS_BETA1   400
#define WS_A2      528
#define WS_S2      656
#define WS_BP      784    // [4][32] PWL breakpoints (floats 784..911)
#define WS_GRAM    5120   // floats 5120..9215
#define WS_SUMY    9216   // floats 9216..9343
#define WS_W2T     17664  // [4][32][32] fp32 (p,c,k)
#define WS_PWL     24576  // [4][33][64] fp32 PWL table: [p][j][A'(32)|B'(32)]
#define WS_MSG_F   262144 // [E][64] fp32 messages (byte 1048576)
#define WS_U00     4456448 // [N][16]  b3_00 @ h0
#define WS_U01     4521984 // [N][16]  b3_01 @ h0
#define WS_V10     4587520 // [N][3q][16m] b3_10 @ h1
#define WS_W11     4784128 // [N][3f*3q][16m] b3_11 @ h1
// int offsets:
#define WS_DEG_I   1024   // ints 1024..5119
#define WS_CUR_I   9344   // ints 9344..13439
#define WS_OFFS_I  13440  // ints 13440..17536
#define WS_ELIST_I 65536  // ints 65536..131071
// byte offsets (weight images, chunk-swizzled: 16B chunk c of col at slot ((col>>1)+c)&3):
#define WSB_WA     524288 // 512 cols x 32 bf16 (32 KB)
#define WSB_WB     557056 // 256 cols p01 (16 KB)
#define WSB_WC     573440 // 768 cols p11 f-major (48 KB)

typedef short bf16x8 __attribute__((ext_vector_type(8)));
typedef float f32x4  __attribute__((ext_vector_type(4)));

__device__ __forceinline__ unsigned short f2bf(float x) {
    unsigned u = __float_as_uint(x);
    u += 0x7fffu + ((u >> 16) & 1u);   // RNE
    return (unsigned short)(u >> 16);
}

// swizzled short-index for element (col, k) of a weight image:
// chunk = k>>3 stored at slot ((col>>1)+chunk)&3
__device__ __forceinline__ int wimg_idx(int col, int k) {
    return col * 32 + ((((col >> 1) + (k >> 3)) & 3) << 3) + (k & 7);
}

// ---------- K1: prep (0-127) + r-stats/degree (128-383) + b3-node tables (384-639) ----------
__global__ void __launch_bounds__(256) k_pre(const float* __restrict__ rw2,
        const float* __restrict__ w300, const float* __restrict__ w301,
        const float* __restrict__ w310, const float* __restrict__ w311,
        const float* __restrict__ bw300, const float* __restrict__ bw301,
        const float* __restrict__ bw310, const float* __restrict__ bw311,
        const float* __restrict__ r, const int* __restrict__ edst,
        const float* __restrict__ h0, const float* __restrict__ h1,
        float* __restrict__ wsf) {
    if (blockIdx.x < 128) {
        int t = blockIdx.x * 256 + threadIdx.x;   // 0..32767
        char* wsb = (char*)wsf;
        if (t < 4096) {   // W2T [p][c][k] <- rw2 [p][k][c]
            int p = t >> 10, rem = t & 1023, c = rem >> 5, k = rem & 31;
            wsf[WS_W2T + t] = rw2[(p << 10) + (k << 5) + c];
        }
        if (t < 16384) {  // image A: p00 | p10 (swizzled)
            int col = t >> 5, k = t & 31;
            float v = (col < 256) ? w300[(k << 8) + col] : w310[(k << 8) + (col - 256)];
            ((unsigned short*)(wsb + WSB_WA))[wimg_idx(col, k)] = f2bf(v);
        }
        if (t < 8192) {   // image B: p01 (swizzled)
            int col = t >> 5, k = t & 31;
            ((unsigned short*)(wsb + WSB_WB))[wimg_idx(col, k)] = f2bf(w301[(k << 8) + col]);
        }
        if (t < 24576) {  // image C: p11 f-major (swizzled)
            int col = t >> 5, k = t & 31;
            int f = col >> 8, rem = col & 255;
            ((unsigned short*)(wsb + WSB_WC))[wimg_idx(col, k)] = f2bf(w311[k * 768 + rem * 3 + f]);
        }
    } else if (blockIdx.x < 384) {
        int e = (blockIdx.x - 128) * 256 + threadIdx.x;   // 0..65535
        float v = r[e];
        atomicAdd(((int*)wsf) + WS_DEG_I + edst[e], 1);
        float s = v, ss = v * v;
#pragma unroll
        for (int mk = 32; mk >= 1; mk >>= 1) {
            s  += __shfl_xor(s,  mk, 64);
            ss += __shfl_xor(ss, mk, 64);
        }
        __shared__ float ls[4], lss[4];
        int lane = threadIdx.x & 63, wv = threadIdx.x >> 6;
        if (lane == 0) { ls[wv] = s; lss[wv] = ss; }
        __syncthreads();
        if (threadIdx.x == 0) {
            atomicAdd(wsf + WS_RSUM,   ls[0] + ls[1] + ls[2] + ls[3]);
            atomicAdd(wsf + WS_RSUMSQ, lss[0] + lss[1] + lss[2] + lss[3]);
        }
    } else {
        int g = (blockIdx.x - 384) * 256 + threadIdx.x;   // 0..65535
        int n = g >> 4, mo = g & 15;
        float h1r[48];
#pragma unroll
        for (int j = 0; j < 48; ++j) h1r[j] = h1[n * 48 + j];
        float s00 = 0.f, s01 = 0.f;
#pragma unroll
        for (int mi = 0; mi < 16; ++mi) {
            float hv = h0[n * 16 + mi];
            s00 += bw300[mo * 16 + mi] * hv;
            s01 += bw301[mo * 16 + mi] * hv;
        }
        wsf[WS_U00 + n * 16 + mo] = s00;
        wsf[WS_U01 + n * 16 + mo] = s01;
#pragma unroll
        for (int q = 0; q < 3; ++q) {
            float sv = 0.f;
#pragma unroll
            for (int mi = 0; mi < 16; ++mi)
                sv += bw310[mo * 16 + mi] * h1r[mi * 3 + q];
            wsf[WS_V10 + n * 48 + q * 16 + mo] = sv;
        }
#pragma unroll
        for (int f = 0; f < 3; ++f)
#pragma unroll
            for (int q = 0; q < 3; ++q) {
                float sv = 0.f;
#pragma unroll
                for (int mi = 0; mi < 16; ++mi)
                    sv += bw311[(mo * 16 + mi) * 3 + f] * h1r[mi * 3 + q];
                wsf[WS_W11 + n * 144 + (f * 3 + q) * 16 + mo] = sv;
            }
    }
}

// ---------- K2: y1 Gram + y1 sum via MFMA ----------
__global__ void __launch_bounds__(512) k_gram(const float* __restrict__ r,
        const float* __restrict__ rw1, const float* __restrict__ rg1,
        const float* __restrict__ rbe1, float* __restrict__ wsf) {
    int t = threadIdx.x;
    int wv = t >> 6, lane = t & 63;
    int quad = lane >> 4, lq = lane & 15;
    int p  = __builtin_amdgcn_readfirstlane(wv & 3);
    int mt = __builtin_amdgcn_readfirstlane(wv >> 2);
    float mu_r  = wsf[WS_RSUM] * (1.f / N_EDGES);
    float var_r = wsf[WS_RSUMSQ] * (1.f / N_EDGES) - mu_r * mu_r;
    float al[2], be[2];
#pragma unroll
    for (int hh = 0; hh < 2; ++hh) {
        int ch = p * 32 + hh * 16 + lq;
        float w1 = rw1[ch];
        float a = w1 * rg1[ch] * rsqrtf(w1 * w1 * var_r + BN_EPS);
        al[hh] = a;
        be[hh] = rbe1[ch] - a * mu_r;
    }
    bf16x8 ones;
#pragma unroll
    for (int j = 0; j < 8; ++j) ones[j] = (short)0x3F80;
    f32x4 accG0 = {0.f, 0.f, 0.f, 0.f};
    f32x4 accG1 = {0.f, 0.f, 0.f, 0.f};
    f32x4 accS  = {0.f, 0.f, 0.f, 0.f};
    int ebase = blockIdx.x * 512;   // grid 128
#pragma unroll 1
    for (int ks = 0; ks < 16; ++ks) {
        const float* rp = r + ebase + ks * 32 + quad * 8;
        float4 ra = *(const float4*)(rp);
        float4 rb = *(const float4*)(rp + 4);
        float rv[8] = {ra.x, ra.y, ra.z, ra.w, rb.x, rb.y, rb.z, rb.w};
        bf16x8 fr0, fr1;
#pragma unroll
        for (int j = 0; j < 8; ++j) {
            fr0[j] = (short)f2bf(fmaxf(0.f, al[0] * rv[j] + be[0]));
            fr1[j] = (short)f2bf(fmaxf(0.f, al[1] * rv[j] + be[1]));
        }
        bf16x8 fA = mt ? fr1 : fr0;
        accG0 = __builtin_amdgcn_mfma_f32_16x16x32_bf16(fA, fr0, accG0, 0, 0, 0);
        accG1 = __builtin_amdgcn_mfma_f32_16x16x32_bf16(fA, fr1, accG1, 0, 0, 0);
        accS  = __builtin_amdgcn_mfma_f32_16x16x32_bf16(fA, ones, accS,  0, 0, 0);
    }
    float* G = wsf + WS_GRAM + p * 1024;
#pragma unroll
    for (int reg = 0; reg < 4; ++reg) {
        int k1 = mt * 16 + quad * 4 + reg;
        atomicAdd(&G[k1 * 32 + lq],      accG0[reg]);
        atomicAdd(&G[k1 * 32 + 16 + lq], accG1[reg]);
    }
    if (lq == 0) {
#pragma unroll
        for (int reg = 0; reg < 4; ++reg)
            atomicAdd(wsf + WS_SUMY + p * 32 + mt * 16 + quad * 4 + reg, accS[reg]);
    }
}

// ---------- K3: fused finalize + prefix scan + PWL table build ----------
__global__ void __launch_bounds__(1024) k_fs(const float* __restrict__ rw1,
        const float* __restrict__ rg1, const float* __restrict__ rbe1,
        const float* __restrict__ rg2, const float* __restrict__ rbe2,
        const float* __restrict__ rb2, float* __restrict__ wsf) {
    int t = threadIdx.x;
    __shared__ float sG[4096];        // [p][k1][k2]
    __shared__ float sW[128 * 33];    // W2T rows, padded +1
    __shared__ float sSumy[128];
    __shared__ float sal[128], sbe[128], sbp[128];
    __shared__ float ssal[128], ssbe[128];
    __shared__ int   ssk[128];
    __shared__ int   sdata[1024];
#pragma unroll
    for (int i = 0; i < 4; ++i) sG[t + i * 1024] = wsf[WS_GRAM + t + i * 1024];
#pragma unroll
    for (int i = 0; i < 4; ++i) {
        int idx = t + i * 1024;
        sW[(idx >> 5) * 33 + (idx & 31)] = wsf[WS_W2T + idx];
    }
    if (t < 128) sSumy[t] = wsf[WS_SUMY + t];
    __syncthreads();

    float a2 = 0.f, s2v = 0.f;
    if (t < 128) {
        float mu_r  = wsf[WS_RSUM] * (1.f / N_EDGES);
        float var_r = wsf[WS_RSUMSQ] * (1.f / N_EDGES) - mu_r * mu_r;
        float w1 = rw1[t];
        float al = w1 * rg1[t] * rsqrtf(w1 * w1 * var_r + BN_EPS);
        float be = rbe1[t] - al * mu_r;
        sal[t] = al;
        sbe[t] = be;
        float bp = (al != 0.f) ? (-be / al) : 3.0e38f;
        sbp[t] = bp;
        wsf[WS_BP + t] = bp;
        int p = t >> 5;
        const float* w = sW + t * 33;
        const float* G = sG + p * 1024;
        float invE = 1.f / N_EDGES;
        float s1 = 0.f;
#pragma unroll
        for (int k = 0; k < 32; ++k) s1 += w[k] * (sSumy[p * 32 + k] * invE);
        float q = 0.f;
#pragma unroll 1
        for (int k1 = 0; k1 < 32; ++k1) {
            float a = 0.f;
#pragma unroll
            for (int k2 = 0; k2 < 32; ++k2) a += w[k2] * G[k1 * 32 + k2];
            q += w[k1] * a;
        }
        float var = q * invE - s1 * s1;
        a2 = rg2[t] * rsqrtf(var + BN_EPS);
        float mu2 = rb2[t] + s1;
        s2v = rbe2[t] - mu2 * a2;
    }
    __syncthreads();
    // rank-sort breakpoints per pair (stable ascending)
    if (t < 128) {
        int p = t >> 5, k = t & 31;
        float mybp = sbp[t];
        int rank = 0;
#pragma unroll
        for (int k2 = 0; k2 < 32; ++k2) {
            float b2 = sbp[p * 32 + k2];
            rank += ((b2 < mybp) || (b2 == mybp && k2 < k)) ? 1 : 0;
        }
        ssal[p * 32 + rank] = sal[t];
        ssbe[p * 32 + rank] = sbe[t];
        ssk [p * 32 + rank] = k;
    }
    __syncthreads();
    if (t < 128) {
        int p = t >> 5, c = t & 31;
        const float* w = sW + t * 33;
        float A = 0.f, B = rb2[t];
#pragma unroll
        for (int k = 0; k < 32; ++k) {
            float ak = sal[p * 32 + k], bk = sbe[p * 32 + k], wk = w[k];
            bool neg = ak < 0.f;
            bool zc  = (ak == 0.f) && (bk > 0.f);
            A += neg ? ak * wk : 0.f;
            B += (neg || zc) ? bk * wk : 0.f;
        }
        float* outp = wsf + WS_PWL + p * 2112 + c;
        outp[0]  = a2 * A;
        outp[32] = a2 * B + s2v;
#pragma unroll
        for (int j = 1; j <= 32; ++j) {
            float ak = ssal[p * 32 + j - 1], bk = ssbe[p * 32 + j - 1];
            int sk = ssk[p * 32 + j - 1];
            float wk = w[sk];
            float sg = (ak > 0.f) ? 1.f : ((ak < 0.f) ? -1.f : 0.f);
            A += sg * ak * wk;
            B += sg * bk * wk;
            outp[j * 64]      = a2 * A;
            outp[j * 64 + 32] = a2 * B + s2v;
        }
    }

    // ---- degree prefix scan ----
    const int* deg = ((const int*)wsf) + WS_DEG_I;
    int* offs = ((int*)wsf) + WS_OFFS_I;
    int* cur  = ((int*)wsf) + WS_CUR_I;
    int v0 = deg[t * 4], v1 = deg[t * 4 + 1], v2 = deg[t * 4 + 2], v3 = deg[t * 4 + 3];
    sdata[t] = v0 + v1 + v2 + v3;
    __syncthreads();
    for (int off = 1; off < 1024; off <<= 1) {
        int x = sdata[t];
        int y = (t >= off) ? sdata[t - off] : 0;
        __syncthreads();
        sdata[t] = x + y;
        __syncthreads();
    }
    int excl = (t == 0) ? 0 : sdata[t - 1];
    int o0 = excl, o1 = excl + v0, o2 = o1 + v1, o3 = o2 + v2;
    offs[t * 4] = o0;     cur[t * 4] = o0;
    offs[t * 4 + 1] = o1; cur[t * 4 + 1] = o1;
    offs[t * 4 + 2] = o2; cur[t * 4 + 2] = o2;
    offs[t * 4 + 3] = o3; cur[t * 4 + 3] = o3;
    if (t == 1023) offs[4096] = sdata[1023];
}

// y2 channels [c0,c0+16) of (pair p, edge el) -> bf16 to LDS via PWL eval.
__device__ __forceinline__ void y2_pwl16(int p, int el, int c0, float rv,
                                         const float* __restrict__ wsf, char* dst) {
    int j = 0;
#pragma unroll
    for (int k4 = 0; k4 < 8; ++k4) {
        float4 bp = *(const float4*)(wsf + WS_BP + p * 32 + k4 * 4);
        j += (rv > bp.x) + (rv > bp.y) + (rv > bp.z) + (rv > bp.w);
    }
    const float* ta = wsf + WS_PWL + p * 2112 + j * 64 + c0;
    unsigned short h[16];
#pragma unroll
    for (int cc = 0; cc < 16; ++cc)
        h[cc] = f2bf(fmaxf(0.f, ta[cc] * rv + ta[32 + cc]));
#pragma unroll
    for (int q = 0; q < 2; ++q) {
        int4 pk;
        pk.x = (int)h[q * 8 + 0] | ((int)h[q * 8 + 1] << 16);
        pk.y = (int)h[q * 8 + 2] | ((int)h[q * 8 + 3] << 16);
        pk.z = (int)h[q * 8 + 4] | ((int)h[q * 8 + 5] << 16);
        pk.w = (int)h[q * 8 + 6] | ((int)h[q * 8 + 7] << 16);
        int jc = (c0 >> 3) + q;
        int slot = ((el >> 1) + jc) & 3;
        *(int4*)(dst + el * 64 + slot * 16) = pk;
    }
}

// ---------- K5a: pairs 00 + 10 -> msg0 (write-only) + edge bucketing ----------
// BLOCK = 1024 (16 waves), 256 edges/block, grid 256; one 16-edge group per
// wave. __launch_bounds__(1024, 4): the second arg (4 waves/EU = 16 waves/CU
// = 1 block/CU) is REQUIRED -- without it the compiler targets an unattainable
// 2-blocks/CU occupancy, caps VGPR at 64 and spills 100+ MB (R8: VGPR=64,
// WRITE 139 MB). At 4 waves/EU the budget is 128 VGPR, which this per-thread
// code fits (proven by R7's 512-thread no-spill runs at VGPR=128).
__global__ void __launch_bounds__(1024, 4) k_msgA(const float* __restrict__ r,
        const float* __restrict__ h0, const float* __restrict__ h1,
        const float* __restrict__ b00, const float* __restrict__ b10,
        const int* __restrict__ esrc, const int* __restrict__ edst,
        float* __restrict__ wsf, float* __restrict__ msg) {
    extern __shared__ char smem[];
    short* w3s = (short*)smem;
    const char* wsb = (const char*)wsf;
    int t = threadIdx.x;
    int wv = t >> 6, lane = t & 63;
    int quad = lane >> 4, lq = lane & 15;
    int eb = blockIdx.x << 8;
    int woff = (((lq >> 1) + quad) & 3) << 3;
    int yoff = (((lq >> 1) + quad) & 3) << 4;
    // bucket this block's 256 edges (was k_bucket)
    if (t < 256) {
        int e2 = eb + t;
        int* cur   = ((int*)wsf) + WS_CUR_I;
        int* elist = ((int*)wsf) + WS_ELIST_I;
        int pos = atomicAdd(&cur[edst[e2]], 1);
        elist[pos] = e2;
    }
    {
        const float4* src = (const float4*)(wsb + WSB_WA);
        float4* dst = (float4*)smem;
#pragma unroll
        for (int i = 0; i < 2; ++i) dst[i * 1024 + t] = src[i * 1024 + t];
    }
    {
        // 1024 jobs: el x {p=0,2} x {c0=0,16}
        int el = t & 255;
        int sel = t >> 8;                         // 0..3
        int p = __builtin_amdgcn_readfirstlane((sel >> 1) * 2);   // 0 or 2
        int c0 = (sel & 1) << 4;
        float rv = r[eb + el];
        char* dst = smem + 32768 + (sel >> 1) * 16384;
        y2_pwl16(p, el, c0, rv, wsf, dst);
    }
    __syncthreads();
    {
        int el = wv * 16 + lq;
        int e = eb + el;
        int s = esrc[e];
        bf16x8 bf0 = *(const bf16x8*)(smem + 32768 + el * 64 + yoff);
        bf16x8 bf2 = *(const bf16x8*)(smem + 49152 + el * 64 + yoff);
        float4 h0q = *(const float4*)(h0 + s * 16 + quad * 4);
        float4 hv0 = *(const float4*)(h1 + s * 48 + quad * 12);
        float4 hv1 = *(const float4*)(h1 + s * 48 + quad * 12 + 4);
        float4 hv2 = *(const float4*)(h1 + s * 48 + quad * 12 + 8);
        float b00v = b00[e];
        float bq0 = b10[e * 3 + 0], bq1 = b10[e * 3 + 1], bq2 = b10[e * 3 + 2];
        float gq0 = bq0 * hv0.x + bq1 * hv0.y + bq2 * hv0.z;
        float gq1 = bq0 * hv0.w + bq1 * hv1.x + bq2 * hv1.y;
        float gq2 = bq0 * hv1.z + bq1 * hv1.w + bq2 * hv2.x;
        float gq3 = bq0 * hv2.y + bq1 * hv2.z + bq2 * hv2.w;
        float4 u00q = *(const float4*)(wsf + WS_U00 + s * 16 + quad * 4);
        float a0[4];
#pragma unroll
        for (int rr = 0; rr < 4; ++rr) a0[rr] = b00v * ((const float*)&u00q)[rr];
#pragma unroll
        for (int q = 0; q < 3; ++q) {
            float4 vq = *(const float4*)(wsf + WS_V10 + s * 48 + q * 16 + quad * 4);
            float bq = (q == 0) ? bq0 : (q == 1) ? bq1 : bq2;
#pragma unroll
            for (int rr = 0; rr < 4; ++rr) a0[rr] += bq * ((const float*)&vq)[rr];
        }
#pragma unroll
        for (int m = 0; m < 16; ++m) {
            bf16x8 af = *(const bf16x8*)(w3s + (m * 16 + lq) * 32 + woff);
            f32x4 dd = __builtin_amdgcn_mfma_f32_16x16x32_bf16(af, bf0, (f32x4){0.f,0.f,0.f,0.f}, 0, 0, 0);
            float partial = dd[0] * h0q.x + dd[1] * h0q.y + dd[2] * h0q.z + dd[3] * h0q.w;
            partial += __shfl_xor(partial, 16);
            partial += __shfl_xor(partial, 32);
            a0[m & 3] += (quad == (m >> 2)) ? b00v * partial : 0.f;
        }
#pragma unroll
        for (int m = 0; m < 16; ++m) {
            bf16x8 af = *(const bf16x8*)(w3s + (256 + m * 16 + lq) * 32 + woff);
            f32x4 dd = __builtin_amdgcn_mfma_f32_16x16x32_bf16(af, bf2, (f32x4){0.f,0.f,0.f,0.f}, 0, 0, 0);
            float partial = dd[0] * gq0 + dd[1] * gq1 + dd[2] * gq2 + dd[3] * gq3;
            partial += __shfl_xor(partial, 16);
            partial += __shfl_xor(partial, 32);
            a0[m & 3] += (quad == (m >> 2)) ? partial : 0.f;
        }
        float4 w = {a0[0], a0[1], a0[2], a0[3]};
        *(float4*)(msg + (size_t)e * 64 + quad * 4) = w;
    }
}

// ---------- K5bc: pairs 01 + 11 -> msg1 (write-once, no RMW) ----------
// BLOCK = 1024 (16 waves), (1024, 4) launch bounds (see k_msgA note: without
// the explicit 4 waves/EU the compiler caps VGPR at 64 and spills -- R8).
// All staging before the single barrier (imgB 16K @0, imgC 48K @16K,
// y2p1 16K @64K, y2p3 16K @80K = 96 KB); no register state crosses it.
__global__ void __launch_bounds__(1024, 4) k_msgBC(const float* __restrict__ r,
        const float* __restrict__ h0, const float* __restrict__ h1,
        const float* __restrict__ b01, const float* __restrict__ b11,
        const int* __restrict__ esrc,
        const float* __restrict__ wsf, float* __restrict__ msg) {
    extern __shared__ char smem[];
    short* w3sB = (short*)smem;                    // cols 0-255 (pair 01)
    short* w3sC = (short*)(smem + 16384);          // cols 0-767 (pair 11, f-major)
    const char* wsb = (const char*)wsf;
    int t = threadIdx.x;
    int wv = t >> 6, lane = t & 63;
    int quad = lane >> 4, lq = lane & 15;
    int eb = blockIdx.x << 8;
    int woff = (((lq >> 1) + quad) & 3) << 3;
    int yoff = (((lq >> 1) + quad) & 3) << 4;
    {
        const float4* srcB = (const float4*)(wsb + WSB_WB);
        float4* dstB = (float4*)smem;
        dstB[t] = srcB[t];
        const float4* srcC = (const float4*)(wsb + WSB_WC);
        float4* dstC = (float4*)(smem + 16384);
#pragma unroll
        for (int i = 0; i < 3; ++i) dstC[i * 1024 + t] = srcC[i * 1024 + t];
    }
    {
        // 1024 jobs: el x {p=1,3} x {c0=0,16}
        int el = t & 255;
        int sel = t >> 8;                         // 0..3
        int p = __builtin_amdgcn_readfirstlane((sel >> 1) * 2 + 1);  // 1 or 3
        int c0 = (sel & 1) << 4;
        float rv = r[eb + el];
        char* dst = smem + 65536 + (sel >> 1) * 16384;
        y2_pwl16(p, el, c0, rv, wsf, dst);
    }
    __syncthreads();
    {
        int el = wv * 16 + lq;
        int e = eb + el;
        int s = esrc[e];
        // ---- B part: pair 01 -> d1, folded into m1 init ----
        bf16x8 bf1 = *(const bf16x8*)(smem + 65536 + el * 64 + yoff);
        float4 h0q = *(const float4*)(h0 + s * 16 + quad * 4);
        float d1[4] = {0.f, 0.f, 0.f, 0.f};
#pragma unroll
        for (int m = 0; m < 16; ++m) {
            bf16x8 af = *(const bf16x8*)(w3sB + (m * 16 + lq) * 32 + woff);
            f32x4 dd = __builtin_amdgcn_mfma_f32_16x16x32_bf16(af, bf1, (f32x4){0.f,0.f,0.f,0.f}, 0, 0, 0);
            float partial = dd[0] * h0q.x + dd[1] * h0q.y + dd[2] * h0q.z + dd[3] * h0q.w;
            partial += __shfl_xor(partial, 16);
            partial += __shfl_xor(partial, 32);
            d1[m & 3] += (quad == (m >> 2)) ? partial : 0.f;
        }
        float bo0 = b01[e * 3 + 0], bo1 = b01[e * 3 + 1], bo2 = b01[e * 3 + 2];
        float4 u01q = *(const float4*)(wsf + WS_U01 + s * 16 + quad * 4);
        float m1[4][3];
#pragma unroll
        for (int rr = 0; rr < 4; ++rr) {
            float u = d1[rr] + ((const float*)&u01q)[rr];
            m1[rr][0] = bo0 * u; m1[rr][1] = bo1 * u; m1[rr][2] = bo2 * u;
        }
        // ---- C part: pair 11 accumulates into m1 ----
        bf16x8 bf3 = *(const bf16x8*)(smem + 81920 + el * 64 + yoff);
        float4 hv0 = *(const float4*)(h1 + s * 48 + quad * 12);
        float4 hv1 = *(const float4*)(h1 + s * 48 + quad * 12 + 4);
        float4 hv2 = *(const float4*)(h1 + s * 48 + quad * 12 + 8);
        float h1v[4][3] = {{hv0.x, hv0.y, hv0.z}, {hv0.w, hv1.x, hv1.y},
                           {hv1.z, hv1.w, hv2.x}, {hv2.y, hv2.z, hv2.w}};
#pragma unroll 1
        for (int f = 0; f < 3; ++f) {
            float bv[3][3];
#pragma unroll
            for (int o = 0; o < 3; ++o)
#pragma unroll
                for (int q = 0; q < 3; ++q)
                    bv[o][q] = b11[(size_t)e * 27 + o * 9 + q * 3 + f];
            // W11 bias-init contribution
#pragma unroll
            for (int q = 0; q < 3; ++q) {
                float4 wq = *(const float4*)(wsf + WS_W11 + s * 144 + (f * 3 + q) * 16 + quad * 4);
#pragma unroll
                for (int o = 0; o < 3; ++o)
#pragma unroll
                    for (int rr = 0; rr < 4; ++rr)
                        m1[rr][o] += bv[o][q] * ((const float*)&wq)[rr];
            }
            // Tf for the MFMA part
            float Tf[4][3];
#pragma unroll
            for (int o = 0; o < 3; ++o)
#pragma unroll
                for (int rr = 0; rr < 4; ++rr)
                    Tf[rr][o] = h1v[rr][0] * bv[o][0] + h1v[rr][1] * bv[o][1] + h1v[rr][2] * bv[o][2];
#pragma unroll
            for (int m = 0; m < 16; ++m) {
                int colb = f * 256 + m * 16 + lq;
                bf16x8 af = *(const bf16x8*)(w3sC + colb * 32 + woff);
                f32x4 dd = __builtin_amdgcn_mfma_f32_16x16x32_bf16(af, bf3, (f32x4){0.f,0.f,0.f,0.f}, 0, 0, 0);
#pragma unroll
                for (int o = 0; o < 3; ++o) {
                    float po = dd[0] * Tf[0][o] + dd[1] * Tf[1][o] + dd[2] * Tf[2][o] + dd[3] * Tf[3][o];
                    po += __shfl_xor(po, 16);
                    po += __shfl_xor(po, 32);
                    m1[m & 3][o] += (quad == (m >> 2)) ? po : 0.f;
                }
            }
        }
        float* base = msg + (size_t)e * 64 + 16 + quad * 12;
        float4 w0 = {m1[0][0], m1[0][1], m1[0][2], m1[1][0]};
        float4 w1 = {m1[1][1], m1[1][2], m1[2][0], m1[2][1]};
        float4 w2 = {m1[2][2], m1[3][0], m1[3][1], m1[3][2]};
        *(float4*)(base)     = w0;
        *(float4*)(base + 4) = w1;
        *(float4*)(base + 8) = w2;
    }
}

// ---------- K6: gather per node, /cnt, + self-interaction ----------
__global__ void __launch_bounds__(256) k_gather(const float* __restrict__ h0,
        const float* __restrict__ h1, const float* __restrict__ Wself0,
        const float* __restrict__ Wself1, const float* __restrict__ wsf,
        float* __restrict__ out) {
    int wv = threadIdx.x >> 6, lane = threadIdx.x & 63;
    int n = blockIdx.x * 4 + wv;     // grid 1024 blocks
    const int* offs  = ((const int*)wsf) + WS_OFFS_I;
    const int* elist = ((const int*)wsf) + WS_ELIST_I;
    const float* msg = wsf + WS_MSG_F;
    int start = offs[n], end = offs[n + 1];
    int deg = end - start;
    float acc = 0.f;
    for (int j0 = 0; j0 < deg; j0 += 64) {
        int cnt = min(64, deg - j0);
        int eidv = (j0 + lane < deg) ? elist[start + j0 + lane] : 0;
        int jj = 0;
        for (; jj + 3 < cnt; jj += 4) {
            int e0 = __shfl(eidv, jj), e1 = __shfl(eidv, jj + 1);
            int e2 = __shfl(eidv, jj + 2), e3 = __shfl(eidv, jj + 3);
            float v0 = msg[(size_t)e0 * 64 + lane];
            float v1 = msg[(size_t)e1 * 64 + lane];
            float v2 = msg[(size_t)e2 * 64 + lane];
            float v3 = msg[(size_t)e3 * 64 + lane];
            acc += (v0 + v1) + (v2 + v3);
        }
        for (; jj < cnt; ++jj) {
            int eid = __shfl(eidv, jj);
            acc += msg[(size_t)eid * 64 + lane];
        }
    }
    float self = 0.f;
    if (lane < 16) {
        int m = lane;
#pragma unroll
        for (int i = 0; i < 16; ++i) self += Wself0[m * 16 + i] * h0[n * 16 + i];
    } else {
        int idx = lane - 16; int m = idx / 3, o = idx % 3;
#pragma unroll
        for (int i = 0; i < 16; ++i) self += Wself1[m * 16 + i] * h1[n * 48 + i * 3 + o];
    }
    float c = (float)(deg > 0 ? deg : 1);
    float res = acc / c + (deg > 0 ? self : 0.f);
    if (lane < 16) out[n * 16 + lane] = res;
    else           out[65536 + n * 48 + (lane - 16)] = res;
}

extern "C" void kernel_launch(void* const* d_in, const int* in_sizes, int n_in,
                              void* d_out, int out_size, void* d_ws, size_t ws_size,
                              hipStream_t stream) {
    const float* h0   = (const float*)d_in[0];
    const float* h1   = (const float*)d_in[1];
    const float* r    = (const float*)d_in[2];
    const float* b00  = (const float*)d_in[3];
    const float* b01  = (const float*)d_in[4];
    const float* b10  = (const float*)d_in[5];
    const float* b11  = (const float*)d_in[6];
    const float* rw1  = (const float*)d_in[7];
    // d_in[8] = rb1: cancels inside BatchNorm
    const float* rg1  = (const float*)d_in[9];
    const float* rbe1 = (const float*)d_in[10];
    const float* rw2  = (const float*)d_in[11];
    const float* rb2  = (const float*)d_in[12];
    const float* rg2  = (const float*)d_in[13];
    const float* rbe2 = (const float*)d_in[14];
    const float* w300 = (const float*)d_in[15];
    const float* bw300= (const float*)d_in[16];
    const float* w301 = (const float*)d_in[17];
    const float* bw301= (const float*)d_in[18];
    const float* w310 = (const float*)d_in[19];
    const float* bw310= (const float*)d_in[20];
    const float* w311 = (const float*)d_in[21];
    const float* bw311= (const float*)d_in[22];
    const float* Wself0 = (const float*)d_in[23];
    const float* Wself1 = (const float*)d_in[24];
    const int* esrc = (const int*)d_in[25];
    const int* edst = (const int*)d_in[26];
    float* out = (float*)d_out;
    float* wsf = (float*)d_ws;
    float* msg = wsf + WS_MSG_F;

    static bool attr_set = false;
    if (!attr_set) {
        hipFuncSetAttribute((const void*)k_msgA,
                            hipFuncAttributeMaxDynamicSharedMemorySize, 65536);
        hipFuncSetAttribute((const void*)k_msgBC,
                            hipFuncAttributeMaxDynamicSharedMemorySize, 98304);
        attr_set = true;
    }

    // single memset: stats + deg + Gram + SUMY (bytes 0..37376)
    hipMemsetAsync(d_ws, 0, 37376, stream);

    k_pre<<<640, 256, 0, stream>>>(rw2, w300, w301, w310, w311,
                                   bw300, bw301, bw310, bw311, r, edst, h0, h1, wsf);
    k_gram<<<128, 512, 0, stream>>>(r, rw1, rg1, rbe1, wsf);
    k_fs<<<1, 1024, 0, stream>>>(rw1, rg1, rbe1, rg2, rbe2, rb2, wsf);
    k_msgA<<<256, 1024, 65536, stream>>>(r, h0, h1, b00, b10, esrc, edst, wsf, msg);
    k_msgBC<<<256, 1024, 98304, stream>>>(r, h0, h1, b01, b11, esrc, wsf, msg);
    k_gather<<<1024, 256, 0, stream>>>(h0, h1, Wself0, Wself1, wsf, out);
}

// Round 10
// 213.784 us; speedup vs baseline: 1.2052x; 1.2052x over previous
//
#include <hip/hip_runtime.h>

#define N_NODES 4096
#define N_EDGES 65536
#define MID 32
#define BN_EPS 1e-5f

// ---- workspace layout ----
// float offsets:
#define WS_RSUM    0
#define WS_RSUMSQ  1
#define WS_ALPHA1  272
#define WS_BETA1   400
#define WS_A2      528
#define WS_S2      656
#define WS_BP      784    // [4][32] PWL breakpoints (floats 784..911)
#define WS_GRAM    5120   // floats 5120..9215
#define WS_SUMY    9216   // floats 9216..9343
#define WS_W2T     17664  // [4][32][32] fp32 (p,c,k)
#define WS_PWL     24576  // [4][33][64] fp32 PWL table: [p][j][A'(32)|B'(32)]
#define WS_MSG_F   262144 // [E][64] fp32 messages (byte 1048576)
#define WS_U00     4456448 // [N][16]  b3_00 @ h0
#define WS_U01     4521984 // [N][16]  b3_01 @ h0
#define WS_V10     4587520 // [N][3q][16m] b3_10 @ h1
#define WS_W11     4784128 // [N][3f*3q][16m] b3_11 @ h1
// int offsets:
#define WS_DEG_I   1024   // ints 1024..5119
#define WS_CUR_I   9344   // ints 9344..13439
#define WS_OFFS_I  13440  // ints 13440..17536
#define WS_ELIST_I 65536  // ints 65536..131071
// byte offsets (weight images, chunk-swizzled: 16B chunk c of col at slot ((col>>1)+c)&3):
#define WSB_WA     524288 // 512 cols x 32 bf16 (32 KB)
#define WSB_WB     557056 // 256 cols p01 (16 KB)
#define WSB_WC     573440 // 768 cols p11 f-major (48 KB)

typedef short bf16x8 __attribute__((ext_vector_type(8)));
typedef float f32x4  __attribute__((ext_vector_type(4)));

__device__ __forceinline__ unsigned short f2bf(float x) {
    unsigned u = __float_as_uint(x);
    u += 0x7fffu + ((u >> 16) & 1u);   // RNE
    return (unsigned short)(u >> 16);
}

// swizzled short-index for element (col, k) of a weight image:
// chunk = k>>3 stored at slot ((col>>1)+chunk)&3
__device__ __forceinline__ int wimg_idx(int col, int k) {
    return col * 32 + ((((col >> 1) + (k >> 3)) & 3) << 3) + (k & 7);
}

// ---------- K1: prep (0-127) + r-stats/degree (128-383) + b3-node tables (384-639) ----------
__global__ void __launch_bounds__(256) k_pre(const float* __restrict__ rw2,
        const float* __restrict__ w300, const float* __restrict__ w301,
        const float* __restrict__ w310, const float* __restrict__ w311,
        const float* __restrict__ bw300, const float* __restrict__ bw301,
        const float* __restrict__ bw310, const float* __restrict__ bw311,
        const float* __restrict__ r, const int* __restrict__ edst,
        const float* __restrict__ h0, const float* __restrict__ h1,
        float* __restrict__ wsf) {
    if (blockIdx.x < 128) {
        int t = blockIdx.x * 256 + threadIdx.x;   // 0..32767
        char* wsb = (char*)wsf;
        if (t < 4096) {   // W2T [p][c][k] <- rw2 [p][k][c]
            int p = t >> 10, rem = t & 1023, c = rem >> 5, k = rem & 31;
            wsf[WS_W2T + t] = rw2[(p << 10) + (k << 5) + c];
        }
        if (t < 16384) {  // image A: p00 | p10 (swizzled)
            int col = t >> 5, k = t & 31;
            float v = (col < 256) ? w300[(k << 8) + col] : w310[(k << 8) + (col - 256)];
            ((unsigned short*)(wsb + WSB_WA))[wimg_idx(col, k)] = f2bf(v);
        }
        if (t < 8192) {   // image B: p01 (swizzled)
            int col = t >> 5, k = t & 31;
            ((unsigned short*)(wsb + WSB_WB))[wimg_idx(col, k)] = f2bf(w301[(k << 8) + col]);
        }
        if (t < 24576) {  // image C: p11 f-major (swizzled)
            int col = t >> 5, k = t & 31;
            int f = col >> 8, rem = col & 255;
            ((unsigned short*)(wsb + WSB_WC))[wimg_idx(col, k)] = f2bf(w311[k * 768 + rem * 3 + f]);
        }
    } else if (blockIdx.x < 384) {
        int e = (blockIdx.x - 128) * 256 + threadIdx.x;   // 0..65535
        float v = r[e];
        atomicAdd(((int*)wsf) + WS_DEG_I + edst[e], 1);
        float s = v, ss = v * v;
#pragma unroll
        for (int mk = 32; mk >= 1; mk >>= 1) {
            s  += __shfl_xor(s,  mk, 64);
            ss += __shfl_xor(ss, mk, 64);
        }
        __shared__ float ls[4], lss[4];
        int lane = threadIdx.x & 63, wv = threadIdx.x >> 6;
        if (lane == 0) { ls[wv] = s; lss[wv] = ss; }
        __syncthreads();
        if (threadIdx.x == 0) {
            atomicAdd(wsf + WS_RSUM,   ls[0] + ls[1] + ls[2] + ls[3]);
            atomicAdd(wsf + WS_RSUMSQ, lss[0] + lss[1] + lss[2] + lss[3]);
        }
    } else {
        int g = (blockIdx.x - 384) * 256 + threadIdx.x;   // 0..65535
        int n = g >> 4, mo = g & 15;
        float h1r[48];
#pragma unroll
        for (int j = 0; j < 48; ++j) h1r[j] = h1[n * 48 + j];
        float s00 = 0.f, s01 = 0.f;
#pragma unroll
        for (int mi = 0; mi < 16; ++mi) {
            float hv = h0[n * 16 + mi];
            s00 += bw300[mo * 16 + mi] * hv;
            s01 += bw301[mo * 16 + mi] * hv;
        }
        wsf[WS_U00 + n * 16 + mo] = s00;
        wsf[WS_U01 + n * 16 + mo] = s01;
#pragma unroll
        for (int q = 0; q < 3; ++q) {
            float sv = 0.f;
#pragma unroll
            for (int mi = 0; mi < 16; ++mi)
                sv += bw310[mo * 16 + mi] * h1r[mi * 3 + q];
            wsf[WS_V10 + n * 48 + q * 16 + mo] = sv;
        }
#pragma unroll
        for (int f = 0; f < 3; ++f)
#pragma unroll
            for (int q = 0; q < 3; ++q) {
                float sv = 0.f;
#pragma unroll
                for (int mi = 0; mi < 16; ++mi)
                    sv += bw311[(mo * 16 + mi) * 3 + f] * h1r[mi * 3 + q];
                wsf[WS_W11 + n * 144 + (f * 3 + q) * 16 + mo] = sv;
            }
    }
}

// ---------- K2: y1 Gram + y1 sum via MFMA ----------
__global__ void __launch_bounds__(512) k_gram(const float* __restrict__ r,
        const float* __restrict__ rw1, const float* __restrict__ rg1,
        const float* __restrict__ rbe1, float* __restrict__ wsf) {
    int t = threadIdx.x;
    int wv = t >> 6, lane = t & 63;
    int quad = lane >> 4, lq = lane & 15;
    int p  = __builtin_amdgcn_readfirstlane(wv & 3);
    int mt = __builtin_amdgcn_readfirstlane(wv >> 2);
    float mu_r  = wsf[WS_RSUM] * (1.f / N_EDGES);
    float var_r = wsf[WS_RSUMSQ] * (1.f / N_EDGES) - mu_r * mu_r;
    float al[2], be[2];
#pragma unroll
    for (int hh = 0; hh < 2; ++hh) {
        int ch = p * 32 + hh * 16 + lq;
        float w1 = rw1[ch];
        float a = w1 * rg1[ch] * rsqrtf(w1 * w1 * var_r + BN_EPS);
        al[hh] = a;
        be[hh] = rbe1[ch] - a * mu_r;
    }
    bf16x8 ones;
#pragma unroll
    for (int j = 0; j < 8; ++j) ones[j] = (short)0x3F80;
    f32x4 accG0 = {0.f, 0.f, 0.f, 0.f};
    f32x4 accG1 = {0.f, 0.f, 0.f, 0.f};
    f32x4 accS  = {0.f, 0.f, 0.f, 0.f};
    int ebase = blockIdx.x * 512;   // grid 128
#pragma unroll 1
    for (int ks = 0; ks < 16; ++ks) {
        const float* rp = r + ebase + ks * 32 + quad * 8;
        float4 ra = *(const float4*)(rp);
        float4 rb = *(const float4*)(rp + 4);
        float rv[8] = {ra.x, ra.y, ra.z, ra.w, rb.x, rb.y, rb.z, rb.w};
        bf16x8 fr0, fr1;
#pragma unroll
        for (int j = 0; j < 8; ++j) {
            fr0[j] = (short)f2bf(fmaxf(0.f, al[0] * rv[j] + be[0]));
            fr1[j] = (short)f2bf(fmaxf(0.f, al[1] * rv[j] + be[1]));
        }
        bf16x8 fA = mt ? fr1 : fr0;
        accG0 = __builtin_amdgcn_mfma_f32_16x16x32_bf16(fA, fr0, accG0, 0, 0, 0);
        accG1 = __builtin_amdgcn_mfma_f32_16x16x32_bf16(fA, fr1, accG1, 0, 0, 0);
        accS  = __builtin_amdgcn_mfma_f32_16x16x32_bf16(fA, ones, accS,  0, 0, 0);
    }
    float* G = wsf + WS_GRAM + p * 1024;
#pragma unroll
    for (int reg = 0; reg < 4; ++reg) {
        int k1 = mt * 16 + quad * 4 + reg;
        atomicAdd(&G[k1 * 32 + lq],      accG0[reg]);
        atomicAdd(&G[k1 * 32 + 16 + lq], accG1[reg]);
    }
    if (lq == 0) {
#pragma unroll
        for (int reg = 0; reg < 4; ++reg)
            atomicAdd(wsf + WS_SUMY + p * 32 + mt * 16 + quad * 4 + reg, accS[reg]);
    }
}

// ---------- K3: fused finalize + prefix scan + PWL table build ----------
__global__ void __launch_bounds__(1024) k_fs(const float* __restrict__ rw1,
        const float* __restrict__ rg1, const float* __restrict__ rbe1,
        const float* __restrict__ rg2, const float* __restrict__ rbe2,
        const float* __restrict__ rb2, float* __restrict__ wsf) {
    int t = threadIdx.x;
    __shared__ float sG[4096];        // [p][k1][k2]
    __shared__ float sW[128 * 33];    // W2T rows, padded +1
    __shared__ float sSumy[128];
    __shared__ float sal[128], sbe[128], sbp[128];
    __shared__ float ssal[128], ssbe[128];
    __shared__ int   ssk[128];
    __shared__ int   sdata[1024];
#pragma unroll
    for (int i = 0; i < 4; ++i) sG[t + i * 1024] = wsf[WS_GRAM + t + i * 1024];
#pragma unroll
    for (int i = 0; i < 4; ++i) {
        int idx = t + i * 1024;
        sW[(idx >> 5) * 33 + (idx & 31)] = wsf[WS_W2T + idx];
    }
    if (t < 128) sSumy[t] = wsf[WS_SUMY + t];
    __syncthreads();

    float a2 = 0.f, s2v = 0.f;
    if (t < 128) {
        float mu_r  = wsf[WS_RSUM] * (1.f / N_EDGES);
        float var_r = wsf[WS_RSUMSQ] * (1.f / N_EDGES) - mu_r * mu_r;
        float w1 = rw1[t];
        float al = w1 * rg1[t] * rsqrtf(w1 * w1 * var_r + BN_EPS);
        float be = rbe1[t] - al * mu_r;
        sal[t] = al;
        sbe[t] = be;
        float bp = (al != 0.f) ? (-be / al) : 3.0e38f;
        sbp[t] = bp;
        wsf[WS_BP + t] = bp;
        int p = t >> 5;
        const float* w = sW + t * 33;
        const float* G = sG + p * 1024;
        float invE = 1.f / N_EDGES;
        float s1 = 0.f;
#pragma unroll
        for (int k = 0; k < 32; ++k) s1 += w[k] * (sSumy[p * 32 + k] * invE);
        float q = 0.f;
#pragma unroll 1
        for (int k1 = 0; k1 < 32; ++k1) {
            float a = 0.f;
#pragma unroll
            for (int k2 = 0; k2 < 32; ++k2) a += w[k2] * G[k1 * 32 + k2];
            q += w[k1] * a;
        }
        float var = q * invE - s1 * s1;
        a2 = rg2[t] * rsqrtf(var + BN_EPS);
        float mu2 = rb2[t] + s1;
        s2v = rbe2[t] - mu2 * a2;
    }
    __syncthreads();
    // rank-sort breakpoints per pair (stable ascending)
    if (t < 128) {
        int p = t >> 5, k = t & 31;
        float mybp = sbp[t];
        int rank = 0;
#pragma unroll
        for (int k2 = 0; k2 < 32; ++k2) {
            float b2 = sbp[p * 32 + k2];
            rank += ((b2 < mybp) || (b2 == mybp && k2 < k)) ? 1 : 0;
        }
        ssal[p * 32 + rank] = sal[t];
        ssbe[p * 32 + rank] = sbe[t];
        ssk [p * 32 + rank] = k;
    }
    __syncthreads();
    if (t < 128) {
        int p = t >> 5, c = t & 31;
        const float* w = sW + t * 33;
        float A = 0.f, B = rb2[t];
#pragma unroll
        for (int k = 0; k < 32; ++k) {
            float ak = sal[p * 32 + k], bk = sbe[p * 32 + k], wk = w[k];
            bool neg = ak < 0.f;
            bool zc  = (ak == 0.f) && (bk > 0.f);
            A += neg ? ak * wk : 0.f;
            B += (neg || zc) ? bk * wk : 0.f;
        }
        float* outp = wsf + WS_PWL + p * 2112 + c;
        outp[0]  = a2 * A;
        outp[32] = a2 * B + s2v;
#pragma unroll
        for (int j = 1; j <= 32; ++j) {
            float ak = ssal[p * 32 + j - 1], bk = ssbe[p * 32 + j - 1];
            int sk = ssk[p * 32 + j - 1];
            float wk = w[sk];
            float sg = (ak > 0.f) ? 1.f : ((ak < 0.f) ? -1.f : 0.f);
            A += sg * ak * wk;
            B += sg * bk * wk;
            outp[j * 64]      = a2 * A;
            outp[j * 64 + 32] = a2 * B + s2v;
        }
    }

    // ---- degree prefix scan ----
    const int* deg = ((const int*)wsf) + WS_DEG_I;
    int* offs = ((int*)wsf) + WS_OFFS_I;
    int* cur  = ((int*)wsf) + WS_CUR_I;
    int v0 = deg[t * 4], v1 = deg[t * 4 + 1], v2 = deg[t * 4 + 2], v3 = deg[t * 4 + 3];
    sdata[t] = v0 + v1 + v2 + v3;
    __syncthreads();
    for (int off = 1; off < 1024; off <<= 1) {
        int x = sdata[t];
        int y = (t >= off) ? sdata[t - off] : 0;
        __syncthreads();
        sdata[t] = x + y;
        __syncthreads();
    }
    int excl = (t == 0) ? 0 : sdata[t - 1];
    int o0 = excl, o1 = excl + v0, o2 = o1 + v1, o3 = o2 + v2;
    offs[t * 4] = o0;     cur[t * 4] = o0;
    offs[t * 4 + 1] = o1; cur[t * 4 + 1] = o1;
    offs[t * 4 + 2] = o2; cur[t * 4 + 2] = o2;
    offs[t * 4 + 3] = o3; cur[t * 4 + 3] = o3;
    if (t == 1023) offs[4096] = sdata[1023];
}

// y2 channels [c0,c0+16) of (pair p, edge el) -> bf16 to LDS via PWL eval.
__device__ __forceinline__ void y2_pwl16(int p, int el, int c0, float rv,
                                         const float* __restrict__ wsf, char* dst) {
    int j = 0;
#pragma unroll
    for (int k4 = 0; k4 < 8; ++k4) {
        float4 bp = *(const float4*)(wsf + WS_BP + p * 32 + k4 * 4);
        j += (rv > bp.x) + (rv > bp.y) + (rv > bp.z) + (rv > bp.w);
    }
    const float* ta = wsf + WS_PWL + p * 2112 + j * 64 + c0;
    unsigned short h[16];
#pragma unroll
    for (int cc = 0; cc < 16; ++cc)
        h[cc] = f2bf(fmaxf(0.f, ta[cc] * rv + ta[32 + cc]));
#pragma unroll
    for (int q = 0; q < 2; ++q) {
        int4 pk;
        pk.x = (int)h[q * 8 + 0] | ((int)h[q * 8 + 1] << 16);
        pk.y = (int)h[q * 8 + 2] | ((int)h[q * 8 + 3] << 16);
        pk.z = (int)h[q * 8 + 4] | ((int)h[q * 8 + 5] << 16);
        pk.w = (int)h[q * 8 + 6] | ((int)h[q * 8 + 7] << 16);
        int jc = (c0 >> 3) + q;
        int slot = ((el >> 1) + jc) & 3;
        *(int4*)(dst + el * 64 + slot * 16) = pk;
    }
}

// ---------- K5a: pairs 00 + 10 -> msg0 (write-only) + edge bucketing ----------
// BLOCK = 512 (8 waves), 256 edges/block, grid 256, 64 KB LDS, VGPR=128.
// RULE (R1/R8/R9, three failed occupancy attempts): this kernel family runs
// at 512 threads / 128 VGPR / 1 block/CU. Grid-doubling never co-resides
// (R1); 1024-thread blocks get VGPR-capped at 64 by the compiler and spill
// 100+ MB regardless of launch_bounds second arg (R8: no arg; R9: (1024,4)).
// Do not retry without new evidence.
__global__ void __launch_bounds__(512, 2) k_msgA(const float* __restrict__ r,
        const float* __restrict__ h0, const float* __restrict__ h1,
        const float* __restrict__ b00, const float* __restrict__ b10,
        const int* __restrict__ esrc, const int* __restrict__ edst,
        float* __restrict__ wsf, float* __restrict__ msg) {
    extern __shared__ char smem[];
    short* w3s = (short*)smem;
    const char* wsb = (const char*)wsf;
    int t = threadIdx.x;
    int wv = t >> 6, lane = t & 63;
    int quad = lane >> 4, lq = lane & 15;
    int eb = blockIdx.x << 8;
    int woff = (((lq >> 1) + quad) & 3) << 3;
    int yoff = (((lq >> 1) + quad) & 3) << 4;
    // bucket this block's 256 edges (was k_bucket)
    if (t < 256) {
        int e2 = eb + t;
        int* cur   = ((int*)wsf) + WS_CUR_I;
        int* elist = ((int*)wsf) + WS_ELIST_I;
        int pos = atomicAdd(&cur[edst[e2]], 1);
        elist[pos] = e2;
    }
    {
        const float4* src = (const float4*)(wsb + WSB_WA);
        float4* dst = (float4*)smem;
#pragma unroll
        for (int i = 0; i < 4; ++i) dst[i * 512 + t] = src[i * 512 + t];
    }
    {
        int p = __builtin_amdgcn_readfirstlane((t >> 8) * 2);   // 0 or 2
        int el = t & 255;
        float rv = r[eb + el];
        char* dst = smem + 32768 + (t >> 8) * 16384;
        y2_pwl16(p, el, 0, rv, wsf, dst);
        y2_pwl16(p, el, 16, rv, wsf, dst);
    }
    __syncthreads();
#pragma unroll 1
    for (int g2 = 0; g2 < 2; ++g2) {
        int el = (wv * 2 + g2) * 16 + lq;
        int e = eb + el;
        int s = esrc[e];
        bf16x8 bf0 = *(const bf16x8*)(smem + 32768 + el * 64 + yoff);
        bf16x8 bf2 = *(const bf16x8*)(smem + 49152 + el * 64 + yoff);
        float4 h0q = *(const float4*)(h0 + s * 16 + quad * 4);
        float4 hv0 = *(const float4*)(h1 + s * 48 + quad * 12);
        float4 hv1 = *(const float4*)(h1 + s * 48 + quad * 12 + 4);
        float4 hv2 = *(const float4*)(h1 + s * 48 + quad * 12 + 8);
        float b00v = b00[e];
        float bq0 = b10[e * 3 + 0], bq1 = b10[e * 3 + 1], bq2 = b10[e * 3 + 2];
        float gq0 = bq0 * hv0.x + bq1 * hv0.y + bq2 * hv0.z;
        float gq1 = bq0 * hv0.w + bq1 * hv1.x + bq2 * hv1.y;
        float gq2 = bq0 * hv1.z + bq1 * hv1.w + bq2 * hv2.x;
        float gq3 = bq0 * hv2.y + bq1 * hv2.z + bq2 * hv2.w;
        float4 u00q = *(const float4*)(wsf + WS_U00 + s * 16 + quad * 4);
        float a0[4];
#pragma unroll
        for (int rr = 0; rr < 4; ++rr) a0[rr] = b00v * ((const float*)&u00q)[rr];
#pragma unroll
        for (int q = 0; q < 3; ++q) {
            float4 vq = *(const float4*)(wsf + WS_V10 + s * 48 + q * 16 + quad * 4);
            float bq = (q == 0) ? bq0 : (q == 1) ? bq1 : bq2;
#pragma unroll
            for (int rr = 0; rr < 4; ++rr) a0[rr] += bq * ((const float*)&vq)[rr];
        }
#pragma unroll
        for (int m = 0; m < 16; ++m) {
            bf16x8 af = *(const bf16x8*)(w3s + (m * 16 + lq) * 32 + woff);
            f32x4 dd = __builtin_amdgcn_mfma_f32_16x16x32_bf16(af, bf0, (f32x4){0.f,0.f,0.f,0.f}, 0, 0, 0);
            float partial = dd[0] * h0q.x + dd[1] * h0q.y + dd[2] * h0q.z + dd[3] * h0q.w;
            partial += __shfl_xor(partial, 16);
            partial += __shfl_xor(partial, 32);
            a0[m & 3] += (quad == (m >> 2)) ? b00v * partial : 0.f;
        }
#pragma unroll
        for (int m = 0; m < 16; ++m) {
            bf16x8 af = *(const bf16x8*)(w3s + (256 + m * 16 + lq) * 32 + woff);
            f32x4 dd = __builtin_amdgcn_mfma_f32_16x16x32_bf16(af, bf2, (f32x4){0.f,0.f,0.f,0.f}, 0, 0, 0);
            float partial = dd[0] * gq0 + dd[1] * gq1 + dd[2] * gq2 + dd[3] * gq3;
            partial += __shfl_xor(partial, 16);
            partial += __shfl_xor(partial, 32);
            a0[m & 3] += (quad == (m >> 2)) ? partial : 0.f;
        }
        float4 w = {a0[0], a0[1], a0[2], a0[3]};
        *(float4*)(msg + (size_t)e * 64 + quad * 4) = w;
    }
}

// ---------- K5bc: pairs 01 + 11 -> msg1 (write-once, no RMW) ----------
// BLOCK = 512 (8 waves), 96 KB LDS, VGPR=128 (see k_msgA rule -- 1024-thread
// variants spill). All staging before the single barrier (imgB 16K @0,
// imgC 48K @16K, y2p1 16K @64K, y2p3 16K @80K = 96 KB); no register state
// crosses it. B-part's d1 folds into m1 before the f-loop.
__global__ void __launch_bounds__(512, 2) k_msgBC(const float* __restrict__ r,
        const float* __restrict__ h0, const float* __restrict__ h1,
        const float* __restrict__ b01, const float* __restrict__ b11,
        const int* __restrict__ esrc,
        const float* __restrict__ wsf, float* __restrict__ msg) {
    extern __shared__ char smem[];
    short* w3sB = (short*)smem;                    // cols 0-255 (pair 01)
    short* w3sC = (short*)(smem + 16384);          // cols 0-767 (pair 11, f-major)
    const char* wsb = (const char*)wsf;
    int t = threadIdx.x;
    int wv = t >> 6, lane = t & 63;
    int quad = lane >> 4, lq = lane & 15;
    int eb = blockIdx.x << 8;
    int woff = (((lq >> 1) + quad) & 3) << 3;
    int yoff = (((lq >> 1) + quad) & 3) << 4;
    {
        const float4* srcB = (const float4*)(wsb + WSB_WB);
        float4* dstB = (float4*)smem;
#pragma unroll
        for (int i = 0; i < 2; ++i) dstB[i * 512 + t] = srcB[i * 512 + t];
        const float4* srcC = (const float4*)(wsb + WSB_WC);
        float4* dstC = (float4*)(smem + 16384);
#pragma unroll
        for (int i = 0; i < 6; ++i) dstC[i * 512 + t] = srcC[i * 512 + t];
    }
    {
        int el = t & 255, c0 = (t >> 8) * 16;
        float rv = r[eb + el];
        y2_pwl16(1, el, c0, rv, wsf, smem + 65536);
        y2_pwl16(3, el, c0, rv, wsf, smem + 81920);
    }
    __syncthreads();
#pragma unroll 1
    for (int g2 = 0; g2 < 2; ++g2) {
        int el = (wv * 2 + g2) * 16 + lq;
        int e = eb + el;
        int s = esrc[e];
        // ---- B part: pair 01 -> d1, folded into m1 init ----
        bf16x8 bf1 = *(const bf16x8*)(smem + 65536 + el * 64 + yoff);
        float4 h0q = *(const float4*)(h0 + s * 16 + quad * 4);
        float d1[4] = {0.f, 0.f, 0.f, 0.f};
#pragma unroll
        for (int m = 0; m < 16; ++m) {
            bf16x8 af = *(const bf16x8*)(w3sB + (m * 16 + lq) * 32 + woff);
            f32x4 dd = __builtin_amdgcn_mfma_f32_16x16x32_bf16(af, bf1, (f32x4){0.f,0.f,0.f,0.f}, 0, 0, 0);
            float partial = dd[0] * h0q.x + dd[1] * h0q.y + dd[2] * h0q.z + dd[3] * h0q.w;
            partial += __shfl_xor(partial, 16);
            partial += __shfl_xor(partial, 32);
            d1[m & 3] += (quad == (m >> 2)) ? partial : 0.f;
        }
        float bo0 = b01[e * 3 + 0], bo1 = b01[e * 3 + 1], bo2 = b01[e * 3 + 2];
        float4 u01q = *(const float4*)(wsf + WS_U01 + s * 16 + quad * 4);
        float m1[4][3];
#pragma unroll
        for (int rr = 0; rr < 4; ++rr) {
            float u = d1[rr] + ((const float*)&u01q)[rr];
            m1[rr][0] = bo0 * u; m1[rr][1] = bo1 * u; m1[rr][2] = bo2 * u;
        }
        // ---- C part: pair 11 accumulates into m1 ----
        bf16x8 bf3 = *(const bf16x8*)(smem + 81920 + el * 64 + yoff);
        float4 hv0 = *(const float4*)(h1 + s * 48 + quad * 12);
        float4 hv1 = *(const float4*)(h1 + s * 48 + quad * 12 + 4);
        float4 hv2 = *(const float4*)(h1 + s * 48 + quad * 12 + 8);
        float h1v[4][3] = {{hv0.x, hv0.y, hv0.z}, {hv0.w, hv1.x, hv1.y},
                           {hv1.z, hv1.w, hv2.x}, {hv2.y, hv2.z, hv2.w}};
#pragma unroll 1
        for (int f = 0; f < 3; ++f) {
            float bv[3][3];
#pragma unroll
            for (int o = 0; o < 3; ++o)
#pragma unroll
                for (int q = 0; q < 3; ++q)
                    bv[o][q] = b11[(size_t)e * 27 + o * 9 + q * 3 + f];
            // W11 bias-init contribution
#pragma unroll
            for (int q = 0; q < 3; ++q) {
                float4 wq = *(const float4*)(wsf + WS_W11 + s * 144 + (f * 3 + q) * 16 + quad * 4);
#pragma unroll
                for (int o = 0; o < 3; ++o)
#pragma unroll
                    for (int rr = 0; rr < 4; ++rr)
                        m1[rr][o] += bv[o][q] * ((const float*)&wq)[rr];
            }
            // Tf for the MFMA part
            float Tf[4][3];
#pragma unroll
            for (int o = 0; o < 3; ++o)
#pragma unroll
                for (int rr = 0; rr < 4; ++rr)
                    Tf[rr][o] = h1v[rr][0] * bv[o][0] + h1v[rr][1] * bv[o][1] + h1v[rr][2] * bv[o][2];
#pragma unroll
            for (int m = 0; m < 16; ++m) {
                int colb = f * 256 + m * 16 + lq;
                bf16x8 af = *(const bf16x8*)(w3sC + colb * 32 + woff);
                f32x4 dd = __builtin_amdgcn_mfma_f32_16x16x32_bf16(af, bf3, (f32x4){0.f,0.f,0.f,0.f}, 0, 0, 0);
#pragma unroll
                for (int o = 0; o < 3; ++o) {
                    float po = dd[0] * Tf[0][o] + dd[1] * Tf[1][o] + dd[2] * Tf[2][o] + dd[3] * Tf[3][o];
                    po += __shfl_xor(po, 16);
                    po += __shfl_xor(po, 32);
                    m1[m & 3][o] += (quad == (m >> 2)) ? po : 0.f;
                }
            }
        }
        float* base = msg + (size_t)e * 64 + 16 + quad * 12;
        float4 w0 = {m1[0][0], m1[0][1], m1[0][2], m1[1][0]};
        float4 w1 = {m1[1][1], m1[1][2], m1[2][0], m1[2][1]};
        float4 w2 = {m1[2][2], m1[3][0], m1[3][1], m1[3][2]};
        *(float4*)(base)     = w0;
        *(float4*)(base + 4) = w1;
        *(float4*)(base + 8) = w2;
    }
}

// ---------- K6: gather per node, /cnt, + self-interaction ----------
__global__ void __launch_bounds__(256) k_gather(const float* __restrict__ h0,
        const float* __restrict__ h1, const float* __restrict__ Wself0,
        const float* __restrict__ Wself1, const float* __restrict__ wsf,
        float* __restrict__ out) {
    int wv = threadIdx.x >> 6, lane = threadIdx.x & 63;
    int n = blockIdx.x * 4 + wv;     // grid 1024 blocks
    const int* offs  = ((const int*)wsf) + WS_OFFS_I;
    const int* elist = ((const int*)wsf) + WS_ELIST_I;
    const float* msg = wsf + WS_MSG_F;
    int start = offs[n], end = offs[n + 1];
    int deg = end - start;
    float acc = 0.f;
    for (int j0 = 0; j0 < deg; j0 += 64) {
        int cnt = min(64, deg - j0);
        int eidv = (j0 + lane < deg) ? elist[start + j0 + lane] : 0;
        int jj = 0;
        for (; jj + 3 < cnt; jj += 4) {
            int e0 = __shfl(eidv, jj), e1 = __shfl(eidv, jj + 1);
            int e2 = __shfl(eidv, jj + 2), e3 = __shfl(eidv, jj + 3);
            float v0 = msg[(size_t)e0 * 64 + lane];
            float v1 = msg[(size_t)e1 * 64 + lane];
            float v2 = msg[(size_t)e2 * 64 + lane];
            float v3 = msg[(size_t)e3 * 64 + lane];
            acc += (v0 + v1) + (v2 + v3);
        }
        for (; jj < cnt; ++jj) {
            int eid = __shfl(eidv, jj);
            acc += msg[(size_t)eid * 64 + lane];
        }
    }
    float self = 0.f;
    if (lane < 16) {
        int m = lane;
#pragma unroll
        for (int i = 0; i < 16; ++i) self += Wself0[m * 16 + i] * h0[n * 16 + i];
    } else {
        int idx = lane - 16; int m = idx / 3, o = idx % 3;
#pragma unroll
        for (int i = 0; i < 16; ++i) self += Wself1[m * 16 + i] * h1[n * 48 + i * 3 + o];
    }
    float c = (float)(deg > 0 ? deg : 1);
    float res = acc / c + (deg > 0 ? self : 0.f);
    if (lane < 16) out[n * 16 + lane] = res;
    else           out[65536 + n * 48 + (lane - 16)] = res;
}

extern "C" void kernel_launch(void* const* d_in, const int* in_sizes, int n_in,
                              void* d_out, int out_size, void* d_ws, size_t ws_size,
                              hipStream_t stream) {
    const float* h0   = (const float*)d_in[0];
    const float* h1   = (const float*)d_in[1];
    const float* r    = (const float*)d_in[2];
    const float* b00  = (const float*)d_in[3];
    const float* b01  = (const float*)d_in[4];
    const float* b10  = (const float*)d_in[5];
    const float* b11  = (const float*)d_in[6];
    const float* rw1  = (const float*)d_in[7];
    // d_in[8] = rb1: cancels inside BatchNorm
    const float* rg1  = (const float*)d_in[9];
    const float* rbe1 = (const float*)d_in[10];
    const float* rw2  = (const float*)d_in[11];
    const float* rb2  = (const float*)d_in[12];
    const float* rg2  = (const float*)d_in[13];
    const float* rbe2 = (const float*)d_in[14];
    const float* w300 = (const float*)d_in[15];
    const float* bw300= (const float*)d_in[16];
    const float* w301 = (const float*)d_in[17];
    const float* bw301= (const float*)d_in[18];
    const float* w310 = (const float*)d_in[19];
    const float* bw310= (const float*)d_in[20];
    const float* w311 = (const float*)d_in[21];
    const float* bw311= (const float*)d_in[22];
    const float* Wself0 = (const float*)d_in[23];
    const float* Wself1 = (const float*)d_in[24];
    const int* esrc = (const int*)d_in[25];
    const int* edst = (const int*)d_in[26];
    float* out = (float*)d_out;
    float* wsf = (float*)d_ws;
    float* msg = wsf + WS_MSG_F;

    static bool attr_set = false;
    if (!attr_set) {
        hipFuncSetAttribute((const void*)k_msgA,
                            hipFuncAttributeMaxDynamicSharedMemorySize, 65536);
        hipFuncSetAttribute((const void*)k_msgBC,
                            hipFuncAttributeMaxDynamicSharedMemorySize, 98304);
        attr_set = true;
    }

    // single memset: stats + deg + Gram + SUMY (bytes 0..37376)
    hipMemsetAsync(d_ws, 0, 37376, stream);

    k_pre<<<640, 256, 0, stream>>>(rw2, w300, w301, w310, w311,
                                   bw300, bw301, bw310, bw311, r, edst, h0, h1, wsf);
    k_gram<<<128, 512, 0, stream>>>(r, rw1, rg1, rbe1, wsf);
    k_fs<<<1, 1024, 0, stream>>>(rw1, rg1, rbe1, rg2, rbe2, rb2, wsf);
    k_msgA<<<256, 512, 65536, stream>>>(r, h0, h1, b00, b10, esrc, edst, wsf, msg);
    k_msgBC<<<256, 512, 98304, stream>>>(r, h0, h1, b01, b11, esrc, wsf, msg);
    k_gather<<<1024, 256, 0, stream>>>(h0, h1, Wself0, Wself1, wsf, out);
}